// Round 4
// baseline (254.627 us; speedup 1.0000x reference)
//
#include <hip/hip_runtime.h>

#define BB   4
#define NGT  20
#define TT   8
#define PP   25600
#define CC   40
#define TPB  1024
#define SUPP 1e9f
#define INNER_TH 0.5f

__device__ inline unsigned long long shfl_down_u64(unsigned long long v, int off) {
    unsigned lo = (unsigned)v, hi = (unsigned)(v >> 32);
    lo = __shfl_down(lo, off, 64);
    hi = __shfl_down(hi, off, 64);
    return ((unsigned long long)hi << 32) | (unsigned long long)lo;
}

// exact distance for grid point (px,py) vs gt geometry g — identical IEEE ops to ref
__device__ inline float point_dist(int px, int py, float4 g) {
    float rxv = __fdiv_rn((float)px + 0.5f, 160.0f);  // == ref_points formula exactly
    float ryv = __fdiv_rn((float)py + 0.5f, 160.0f);
    float dx = __fdiv_rn(__fsub_rn(g.x, rxv), g.z);
    float dy = __fdiv_rn(__fsub_rn(g.y, ryv), g.w);
    return __fadd_rn(__fmul_rn(dx, dx), __fmul_rn(dy, dy));  // no FMA contraction
}

// ---------------- match: one block per (b,t); inline prep; writes ml/mi fully,
// ---------------- records (cls,score) per point in ws for the md paint pass.
__global__ __launch_bounds__(TPB) void match_kernel(
        const int*   __restrict__ gt_labels,
        const float* __restrict__ gt_boxes,
        const int*   __restrict__ gt_ids,
        int*   __restrict__ ws_cls,    // [B*T][P]  -1 = no record
        float* __restrict__ ws_score,  // [B*T][P]  valid iff ws_cls >= 0
        float* __restrict__ out) {
    int bt = blockIdx.x;            // b*T + t
    int b  = bt >> 3;
    int t  = bt & 7;
    int tid = threadIdx.x;

    __shared__ unsigned char s_claimed[PP];   // 25600 B
    __shared__ float  s_area[NGT];
    __shared__ int    s_valid[NGT];
    __shared__ int    s_order[NGT];
    __shared__ int    s_any[NGT];             // one flag per gt: never reused
    __shared__ float4 s_geo[NGT];
    __shared__ int4   s_meta[NGT];
    __shared__ unsigned long long s_wave[16];
    __shared__ unsigned long long s_bcast;

    float* ml   = out + (size_t)bt * PP;
    float* mi   = out + (size_t)BB * TT * PP * (1 + CC) + (size_t)bt * PP;
    int*   wcls = ws_cls   + (size_t)bt * PP;
    float* wsc  = ws_score + (size_t)bt * PP;

    // ---- phase 0: zero claimed, default ml/mi/-1 and cls/-1, per-gt mean area ----
    for (int i = tid; i < PP / 4; i += TPB) ((int*)s_claimed)[i] = 0;
    for (int i = tid; i < PP; i += TPB) { ml[i] = -1.0f; mi[i] = -1.0f; wcls[i] = -1; }
    if (tid < NGT) {
        const float* bx = gt_boxes + (size_t)(b * NGT + tid) * TT * 4;
        float a[TT];
        int anyPos = 0;
        for (int f = 0; f < TT; f++) {
            float w = __fsub_rn(bx[f * 4 + 2], bx[f * 4 + 0]);
            float h = __fsub_rn(bx[f * 4 + 3], bx[f * 4 + 1]);
            a[f] = __fmul_rn(w, h);
            anyPos |= (w > 0.0f && h > 0.0f) ? 1 : 0;
        }
        // numpy pairwise sum order for n=8, then * 1/8
        float s = __fadd_rn(__fadd_rn(__fadd_rn(a[0], a[1]), __fadd_rn(a[2], a[3])),
                            __fadd_rn(__fadd_rn(a[4], a[5]), __fadd_rn(a[6], a[7])));
        s_area[tid]  = __fmul_rn(s, 0.125f);
        s_valid[tid] = (anyPos && gt_labels[b * NGT + tid] >= 0) ? 1 : 0;
        s_any[tid]   = 0;
    }
    __syncthreads();

    // ---- phase 1: stable ascending argsort by rank counting ----
    if (tid < NGT) {
        float an = s_area[tid];
        int r = 0;
        for (int m2 = 0; m2 < NGT; m2++) {
            float am = s_area[m2];
            r += (am < an || (am == an && m2 < tid)) ? 1 : 0;
        }
        s_order[r] = tid;
    }
    __syncthreads();

    // ---- phase 2: per sorted slot, load this frame's geometry/meta ----
    if (tid < NGT) {
        int n   = s_order[tid];
        int src = b * NGT + n;
        const float* bx = gt_boxes + ((size_t)src * TT + t) * 4;
        float x1 = bx[0], y1 = bx[1], x2 = bx[2], y2 = bx[3];
        float4 g;
        g.x = __fmul_rn(__fadd_rn(x1, x2), 0.5f);
        g.y = __fmul_rn(__fadd_rn(y1, y2), 0.5f);
        g.z = fmaxf(__fsub_rn(x2, x1), 0.05f);
        g.w = fmaxf(__fsub_rn(y2, y1), 0.05f);
        s_geo[tid] = g;
        int id = gt_ids[src * TT + t];
        int4 mm;
        mm.x = gt_labels[src];
        mm.y = id;
        mm.z = (s_valid[n] && id != -1) ? 1 : 0;
        mm.w = 0;
        s_meta[tid] = mm;
    }
    // loop-top barrier covers phase-2 visibility for n=0

    for (int n = 0; n < NGT; n++) {
        __syncthreads();                       // A: prior claims + phase data visible
        int4 m = s_meta[n];
        if (!m.z) continue;                    // uniform across block
        float4 g = s_geo[n];

        // conservative rect: superset of {d < 0.5} (|dx_norm| < sqrt(0.5) per axis), +/-1 cell slop
        float ex = __fmul_rn(g.z, 0.70711f);
        float ey = __fmul_rn(g.w, 0.70711f);
        int x0 = max(0,   (int)floorf((g.x - ex) * 160.0f - 0.5f) - 1);
        int x1 = min(159, (int)ceilf ((g.x + ex) * 160.0f - 0.5f) + 1);
        int y0 = max(0,   (int)floorf((g.y - ey) * 160.0f - 0.5f) - 1);
        int y1 = min(159, (int)ceilf ((g.y + ey) * 160.0f - 0.5f) + 1);
        int rw = x1 - x0 + 1;
        int M  = rw * (y1 - y0 + 1);

        // pass 1: any unclaimed inner point in rect? (== ref inner.any(): claimed hold 1e9)
        int found = 0;
        for (int i = tid; i < M; i += TPB) {
            int r  = i / rw;
            int px = x0 + (i - r * rw);
            int py = y0 + r;
            int p  = py * 160 + px;
            if (!s_claimed[p]) {
                float d = point_dist(px, py, g);
                if (d < INNER_TH) found = 1;
            }
        }
        if (found) s_any[n] = 1;
        __syncthreads();                       // B
        int any = s_any[n];

        if (any) {
            // pass 2: claim all unclaimed inner points (each p scanned by exactly one thread)
            float labf = (float)m.x, idf = (float)m.y;
            for (int i = tid; i < M; i += TPB) {
                int r  = i / rw;
                int px = x0 + (i - r * rw);
                int py = y0 + r;
                int p  = py * 160 + px;
                if (!s_claimed[p]) {
                    float d = point_dist(px, py, g);
                    if (d < INNER_TH) {
                        s_claimed[p] = 1;
                        ml[p] = labf;
                        mi[p] = idf;
                        wcls[p] = m.x;
                        // d < 0.5 => clip(d,0,0.5)=d => score = 1 - 2d exactly
                        wsc[p] = __fsub_rn(1.0f, __fmul_rn(2.0f, d));
                    }
                }
            }
        } else {
            // fallback: single argmin over suppressed full frame.
            // inside rect no unclaimed d<0.5; outside rect d>=0.5; claimed = 1e9
            // => winner score = 1 - 2*clip(d,0,0.5) = 0 exactly (identity on zeroed md),
            //    EXCEPT winner-was-claimed (all claimed) where ref md[p][lab]=0 may erase
            //    a prior same-class record — handled below.
            unsigned long long key = ~0ULL;
            for (int p = tid; p < PP; p += TPB) {
                float deff;
                if (s_claimed[p]) {
                    deff = SUPP;               // == ref's suppressed value exactly
                } else {
                    int py = p / 160;
                    int px = p - py * 160;
                    deff = point_dist(px, py, g);
                }
                unsigned long long kk =
                    ((unsigned long long)__float_as_uint(deff) << 32) |
                    (unsigned long long)(unsigned)p;
                key = (kk < key) ? kk : key;
            }
            unsigned long long v = key;
            for (int off = 32; off > 0; off >>= 1) {
                unsigned long long o = shfl_down_u64(v, off);
                v = (o < v) ? o : v;
            }
            int lane = tid & 63, wave = tid >> 6;
            if (lane == 0) s_wave[wave] = v;
            __syncthreads();
            if (tid == 0) {
                unsigned long long mval = s_wave[0];
                for (int w = 1; w < 16; w++) mval = (s_wave[w] < mval) ? s_wave[w] : mval;
                s_bcast = mval;
            }
            __syncthreads();
            unsigned long long gmin = s_bcast;
            float minv = __uint_as_float((unsigned)(gmin >> 32));
            int minp = (int)(unsigned)(gmin & 0xffffffffu);
            if ((minp & (TPB - 1)) == tid) {   // unique owner thread
                s_claimed[minp] = 1;
                ml[minp] = (float)m.x;
                mi[minp] = (float)m.y;
                if (minv >= SUPP) {
                    // all points claimed: ref writes md[minp][m.x] = 0 over whatever was there
                    if (wcls[minp] == m.x) wcls[minp] = -1;
                }
                // else: minp was unclaimed => no record => md row stays zero (exact)
            }
            // claims + s_wave reuse guarded by barrier A next iteration
        }
    }
}

// ---------------- paint: write the entire md region exactly once ----------------
__global__ __launch_bounds__(256) void paint_md(
        const int*   __restrict__ ws_cls,
        const float* __restrict__ ws_score,
        float4* __restrict__ md4) {
    const int total4 = BB * TT * PP * CC / 4;     // 8,192,000 float4s
    int stride = gridDim.x * blockDim.x;
    for (int j = blockIdx.x * blockDim.x + threadIdx.x; j < total4; j += stride) {
        unsigned pt = (unsigned)j / 10u;          // point index (40 classes = 10 float4s)
        int c0 = (int)((unsigned)j - pt * 10u) * 4;
        int cls = ws_cls[pt];
        float4 v = make_float4(0.0f, 0.0f, 0.0f, 0.0f);
        if (cls >= c0 && cls < c0 + 4) {          // cls == -1 never matches (c0 >= 0)
            ((float*)&v)[cls - c0] = ws_score[pt];
        }
        md4[j] = v;
    }
}

extern "C" void kernel_launch(void* const* d_in, const int* in_sizes, int n_in,
                              void* d_out, int out_size, void* d_ws, size_t ws_size,
                              hipStream_t stream) {
    const int*   gt_labels = (const int*)d_in[0];
    const float* gt_boxes  = (const float*)d_in[1];
    const int*   gt_ids    = (const int*)d_in[2];
    // d_in[3] = ref_points (regular 160x160 grid — computed exactly in-kernel)
    // d_in[4] = spatial_shapes (unused; H=W=160 fixed)
    float* out = (float*)d_out;

    int*   ws_cls   = (int*)d_ws;
    float* ws_score = (float*)((char*)d_ws + (size_t)BB * TT * PP * sizeof(int));

    match_kernel<<<BB * TT, TPB, 0, stream>>>(gt_labels, gt_boxes, gt_ids,
                                              ws_cls, ws_score, out);
    float4* md4 = (float4*)(out + (size_t)BB * TT * PP);
    paint_md<<<8000, 256, 0, stream>>>(ws_cls, ws_score, md4);
}

// Round 5
// 239.904 us; speedup vs baseline: 1.0614x; 1.0614x over previous
//
#include <hip/hip_runtime.h>

#define BB   4
#define NGT  20
#define TT   8
#define PP   25600
#define CC   40
#define TPB  1024
#define SUPP 1e9f
#define INNER_TH 0.5f

// pack bits: [0]=claimed  [1:6]=ml label  [7:13]=mi id  [14]=md valid  [15:20]=md class
#define PK_CLAIM  1u
#define PK_LAB_SH 1
#define PK_ID_SH  7
#define PK_MDV    (1u << 14)
#define PK_MDC_SH 15

__device__ inline unsigned long long shfl_down_u64(unsigned long long v, int off) {
    unsigned lo = (unsigned)v, hi = (unsigned)(v >> 32);
    lo = __shfl_down(lo, off, 64);
    hi = __shfl_down(hi, off, 64);
    return ((unsigned long long)hi << 32) | (unsigned long long)lo;
}

// exact distance for grid point (px,py) vs gt geometry g — identical IEEE ops to ref
__device__ inline float point_dist(int px, int py, float4 g) {
    float rxv = __fdiv_rn((float)px + 0.5f, 160.0f);  // == ref_points formula exactly
    float ryv = __fdiv_rn((float)py + 0.5f, 160.0f);
    float dx = __fdiv_rn(__fsub_rn(g.x, rxv), g.z);
    float dy = __fdiv_rn(__fsub_rn(g.y, ryv), g.w);
    return __fadd_rn(__fmul_rn(dx, dx), __fmul_rn(dy, dy));  // no FMA contraction
}

// ---------------- match: one block per (b,t); all state in LDS; dumps pack + scores ----
__global__ __launch_bounds__(TPB) void match_kernel(
        const int*   __restrict__ gt_labels,
        const float* __restrict__ gt_boxes,
        const int*   __restrict__ gt_ids,
        unsigned* __restrict__ packs_g,   // [B*T][P]
        float*    __restrict__ scores_g) { // [B*T][P], written only where md-valid
    int bt = blockIdx.x;            // b*T + t
    int b  = bt >> 3;
    int t  = bt & 7;
    int tid = threadIdx.x;

    __shared__ unsigned s_pack[PP];           // 102400 B
    __shared__ float  s_area[NGT];
    __shared__ int    s_valid[NGT];
    __shared__ int    s_order[NGT];
    __shared__ int    s_any[NGT];             // one flag per gt: never reused
    __shared__ float4 s_geo[NGT];
    __shared__ int4   s_meta[NGT];
    __shared__ unsigned long long s_wave[16];
    __shared__ unsigned long long s_bcast;

    unsigned* pk_out = packs_g  + (size_t)bt * PP;
    float*    sc_out = scores_g + (size_t)bt * PP;

    // ---- phase 0: zero pack state, per-gt mean area / validity ----
    for (int i = tid; i < PP; i += TPB) s_pack[i] = 0u;
    if (tid < NGT) {
        const float* bx = gt_boxes + (size_t)(b * NGT + tid) * TT * 4;
        float a[TT];
        int anyPos = 0;
        for (int f = 0; f < TT; f++) {
            float w = __fsub_rn(bx[f * 4 + 2], bx[f * 4 + 0]);
            float h = __fsub_rn(bx[f * 4 + 3], bx[f * 4 + 1]);
            a[f] = __fmul_rn(w, h);
            anyPos |= (w > 0.0f && h > 0.0f) ? 1 : 0;
        }
        // numpy pairwise sum order for n=8, then * 1/8
        float s = __fadd_rn(__fadd_rn(__fadd_rn(a[0], a[1]), __fadd_rn(a[2], a[3])),
                            __fadd_rn(__fadd_rn(a[4], a[5]), __fadd_rn(a[6], a[7])));
        s_area[tid]  = __fmul_rn(s, 0.125f);
        s_valid[tid] = (anyPos && gt_labels[b * NGT + tid] >= 0) ? 1 : 0;
        s_any[tid]   = 0;
    }
    __syncthreads();

    // ---- phase 1: stable ascending argsort by rank counting ----
    if (tid < NGT) {
        float an = s_area[tid];
        int r = 0;
        for (int m2 = 0; m2 < NGT; m2++) {
            float am = s_area[m2];
            r += (am < an || (am == an && m2 < tid)) ? 1 : 0;
        }
        s_order[r] = tid;
    }
    __syncthreads();

    // ---- phase 2: per sorted slot, this frame's geometry/meta ----
    if (tid < NGT) {
        int n   = s_order[tid];
        int src = b * NGT + n;
        const float* bx = gt_boxes + ((size_t)src * TT + t) * 4;
        float x1 = bx[0], y1 = bx[1], x2 = bx[2], y2 = bx[3];
        float4 g;
        g.x = __fmul_rn(__fadd_rn(x1, x2), 0.5f);
        g.y = __fmul_rn(__fadd_rn(y1, y2), 0.5f);
        g.z = fmaxf(__fsub_rn(x2, x1), 0.05f);
        g.w = fmaxf(__fsub_rn(y2, y1), 0.05f);
        s_geo[tid] = g;
        int id = gt_ids[src * TT + t];
        int4 mm;
        mm.x = gt_labels[src];
        mm.y = id;
        mm.z = (s_valid[n] && id != -1) ? 1 : 0;
        mm.w = 0;
        s_meta[tid] = mm;
    }
    // loop-top barrier covers phase-2 visibility for n=0

    for (int n = 0; n < NGT; n++) {
        __syncthreads();                       // A: prior claims + phase data visible
        int4 m = s_meta[n];
        if (!m.z) continue;                    // uniform across block
        float4 g = s_geo[n];

        // conservative rect: superset of {d < 0.5} (|dx_n| < sqrt(0.5) per axis), +slop
        float ex = __fmul_rn(g.z, 0.70711f);   // 0.70711 > sqrt(0.5), + cell slop below
        float ey = __fmul_rn(g.w, 0.70711f);
        int x0 = max(0,   (int)floorf((g.x - ex) * 160.0f - 0.5f) - 1);
        int x1 = min(159, (int)ceilf ((g.x + ex) * 160.0f - 0.5f) + 1);
        int y0 = max(0,   (int)floorf((g.y - ey) * 160.0f - 0.5f) - 1);
        int y1 = min(159, (int)ceilf ((g.y + ey) * 160.0f - 0.5f) + 1);
        int rw = x1 - x0 + 1;
        int M  = rw * (y1 - y0 + 1);           // <= ~73*73 < 6*TPB

        // pass 1: any unclaimed inner point? cache d in registers for pass 2.
        float dcache[6];
        int found = 0;
        {
            int k = 0;
            for (int i = tid; i < M; i += TPB, k++) {
                int r  = i / rw;
                int px = x0 + (i - r * rw);
                int py = y0 + r;
                int p  = py * 160 + px;
                float d = SUPP;
                if (!(s_pack[p] & PK_CLAIM)) {
                    d = point_dist(px, py, g);
                    if (d < INNER_TH) found = 1;
                }
                dcache[k] = d;
            }
        }
        if (found) s_any[n] = 1;
        __syncthreads();                       // B (no state writes between A..B scans)
        int any = s_any[n];

        if (any) {
            // pass 2: claim all unclaimed inner points (each p scanned by one thread;
            // claimed-state unchanged since pass 1, d cached)
            unsigned base = PK_CLAIM | ((unsigned)m.x << PK_LAB_SH) |
                            ((unsigned)m.y << PK_ID_SH) | PK_MDV |
                            ((unsigned)m.x << PK_MDC_SH);
            int k = 0;
            for (int i = tid; i < M; i += TPB, k++) {
                float d = dcache[k];
                if (d < INNER_TH) {            // implies was-unclaimed in pass 1
                    int r  = i / rw;
                    int px = x0 + (i - r * rw);
                    int p  = (y0 + r) * 160 + px;
                    s_pack[p] = base;
                    // d < 0.5 => clip(d,0,0.5)=d => score = 1 - 2d exactly
                    sc_out[p] = __fsub_rn(1.0f, __fmul_rn(2.0f, d));
                }
            }
        } else {
            // fallback: single argmin over suppressed full frame (exact ref semantics:
            // claimed points hold 1e9; ties -> first index).
            unsigned long long key = ~0ULL;
            for (int p = tid; p < PP; p += TPB) {
                float deff;
                if (s_pack[p] & PK_CLAIM) {
                    deff = SUPP;
                } else {
                    int py = p / 160;
                    int px = p - py * 160;
                    deff = point_dist(px, py, g);
                }
                unsigned long long kk =
                    ((unsigned long long)__float_as_uint(deff) << 32) |
                    (unsigned long long)(unsigned)p;
                key = (kk < key) ? kk : key;
            }
            unsigned long long v = key;
            for (int off = 32; off > 0; off >>= 1) {
                unsigned long long o = shfl_down_u64(v, off);
                v = (o < v) ? o : v;
            }
            int lane = tid & 63, wave = tid >> 6;
            if (lane == 0) s_wave[wave] = v;
            __syncthreads();
            if (tid == 0) {
                unsigned long long mval = s_wave[0];
                for (int w = 1; w < 16; w++) mval = (s_wave[w] < mval) ? s_wave[w] : mval;
                s_bcast = mval;
            }
            __syncthreads();
            unsigned long long gmin = s_bcast;
            float minv = __uint_as_float((unsigned)(gmin >> 32));
            int minp = (int)(unsigned)(gmin & 0xffffffffu);
            if ((minp & (TPB - 1)) == tid) {   // unique owner thread
                unsigned npk = PK_CLAIM | ((unsigned)m.x << PK_LAB_SH) |
                               ((unsigned)m.y << PK_ID_SH);
                if (minv < SUPP) {
                    // winner was unclaimed: d >= 0.5 (none inner in rect, outside rect
                    // d >= 0.5) => ref md write = 0 on an all-zero row: no md record.
                    s_pack[minp] = npk;
                } else {
                    // all points claimed (ref: argmin of all-1e9 = index 0). ref writes
                    // md[minp][lab] = 0: erase prior record iff same class; ml/mi updated.
                    unsigned old = s_pack[minp];
                    unsigned mdbits = old & (PK_MDV | (63u << PK_MDC_SH));
                    if ((old & PK_MDV) &&
                        ((old >> PK_MDC_SH) & 63u) == (unsigned)m.x) mdbits = 0u;
                    s_pack[minp] = npk | mdbits;
                }
            }
            // claims + s_wave reuse guarded by barrier A next iteration
        }
    }

    // ---- dump pack state (coalesced) ----
    __syncthreads();
    for (int i = tid; i < PP; i += TPB) pk_out[i] = s_pack[i];
}

// ---------------- paint: write ml | md | mi, every output byte exactly once ----------
__global__ __launch_bounds__(256) void paint_kernel(
        const unsigned* __restrict__ packs,
        const float*    __restrict__ scores,
        float4* __restrict__ out4) {
    const int ML4  = BB * TT * PP / 4;            // 204800
    const int MD4  = BB * TT * PP * CC / 4;       // 8192000
    const int TOT4 = ML4 + MD4 + ML4;             // 8601600
    int stride = gridDim.x * blockDim.x;
    for (int j = blockIdx.x * blockDim.x + threadIdx.x; j < TOT4; j += stride) {
        float4 v;
        if (j < ML4) {                            // ml: label or -1
            int p4 = j << 2;
#pragma unroll
            for (int k = 0; k < 4; k++) {
                unsigned pk = packs[p4 + k];
                ((float*)&v)[k] = (pk & PK_CLAIM)
                    ? (float)((pk >> PK_LAB_SH) & 63u) : -1.0f;
            }
        } else if (j < ML4 + MD4) {               // md: one-hot score row
            unsigned idx = (unsigned)(j - ML4);
            unsigned pt  = idx / 10u;             // 10 float4s per point (40 classes)
            int c0 = (int)(idx - pt * 10u) << 2;
            unsigned pk = packs[pt];
            v = make_float4(0.0f, 0.0f, 0.0f, 0.0f);
            if (pk & PK_MDV) {
                int mc = (int)((pk >> PK_MDC_SH) & 63u);
                if (mc >= c0 && mc < c0 + 4) ((float*)&v)[mc - c0] = scores[pt];
            }
        } else {                                  // mi: id or -1
            int p4 = (j - ML4 - MD4) << 2;
#pragma unroll
            for (int k = 0; k < 4; k++) {
                unsigned pk = packs[p4 + k];
                ((float*)&v)[k] = (pk & PK_CLAIM)
                    ? (float)((pk >> PK_ID_SH) & 127u) : -1.0f;
            }
        }
        out4[j] = v;
    }
}

extern "C" void kernel_launch(void* const* d_in, const int* in_sizes, int n_in,
                              void* d_out, int out_size, void* d_ws, size_t ws_size,
                              hipStream_t stream) {
    const int*   gt_labels = (const int*)d_in[0];
    const float* gt_boxes  = (const float*)d_in[1];
    const int*   gt_ids    = (const int*)d_in[2];
    // d_in[3] = ref_points (regular 160x160 grid — computed exactly in-kernel)
    // d_in[4] = spatial_shapes (unused; H=W=160 fixed)

    unsigned* packs  = (unsigned*)d_ws;                               // 3.2 MB
    float*    scores = (float*)((char*)d_ws + (size_t)BB * TT * PP * 4); // 3.2 MB

    match_kernel<<<BB * TT, TPB, 0, stream>>>(gt_labels, gt_boxes, gt_ids,
                                              packs, scores);
    paint_kernel<<<8400, 256, 0, stream>>>(packs, scores, (float4*)d_out);
}

// Round 6
// 228.387 us; speedup vs baseline: 1.1149x; 1.0504x over previous
//
#include <hip/hip_runtime.h>

#define BB   4
#define NGT  20
#define TT   8
#define PP   25600
#define CC   40
#define TPB  1024
#define SUPP 1e9f
#define INNER_TH 0.5f

// pack bits: [0]=claimed [1:6]=ml label [7:13]=mi id [14]=md valid
//            [15:20]=md class [21:25]=md raw-gt-index (for exact score recompute)
#define PK_CLAIM  1u
#define PK_LAB_SH 1
#define PK_ID_SH  7
#define PK_MDV    (1u << 14)
#define PK_MDC_SH 15
#define PK_MDN_SH 21

__device__ inline unsigned long long shfl_down_u64(unsigned long long v, int off) {
    unsigned lo = (unsigned)v, hi = (unsigned)(v >> 32);
    lo = __shfl_down(lo, off, 64);
    hi = __shfl_down(hi, off, 64);
    return ((unsigned long long)hi << 32) | (unsigned long long)lo;
}

// geometry for (b, raw n, t) — identical IEEE ops in match and paint
__device__ inline float4 make_geo(const float* __restrict__ gt_boxes, int b, int n, int t) {
    const float* bx = gt_boxes + ((size_t)(b * NGT + n) * TT + t) * 4;
    float x1 = bx[0], y1 = bx[1], x2 = bx[2], y2 = bx[3];
    float4 g;
    g.x = __fmul_rn(__fadd_rn(x1, x2), 0.5f);
    g.y = __fmul_rn(__fadd_rn(y1, y2), 0.5f);
    g.z = fmaxf(__fsub_rn(x2, x1), 0.05f);
    g.w = fmaxf(__fsub_rn(y2, y1), 0.05f);
    return g;
}

// exact distance for grid point (px,py) vs gt geometry g — identical IEEE ops to ref
__device__ inline float point_dist(int px, int py, float4 g) {
    float rxv = __fdiv_rn((float)px + 0.5f, 160.0f);  // == ref_points formula exactly
    float ryv = __fdiv_rn((float)py + 0.5f, 160.0f);
    float dx = __fdiv_rn(__fsub_rn(g.x, rxv), g.z);
    float dy = __fdiv_rn(__fsub_rn(g.y, ryv), g.w);
    return __fadd_rn(__fmul_rn(dx, dx), __fmul_rn(dy, dy));  // no FMA contraction
}

// ---------------- match: one block per (b,t); pure-LDS loop; one coalesced dump ----
__global__ __launch_bounds__(TPB) void match_kernel(
        const int*   __restrict__ gt_labels,
        const float* __restrict__ gt_boxes,
        const int*   __restrict__ gt_ids,
        unsigned* __restrict__ packs_g) {  // [B*T][P]
    int bt = blockIdx.x;            // b*T + t
    int b  = bt >> 3;
    int t  = bt & 7;
    int tid = threadIdx.x;

    __shared__ unsigned s_pack[PP];           // 102400 B
    __shared__ float  s_area[NGT];
    __shared__ int    s_valid[NGT];
    __shared__ int    s_order[NGT];
    __shared__ int    s_any[NGT];             // one flag per gt: never reused
    __shared__ float4 s_geo[NGT];
    __shared__ int4   s_meta[NGT];            // {label, id, active, raw n}
    __shared__ unsigned long long s_wave[16];
    __shared__ unsigned long long s_bcast;

    // ---- phase 0: zero pack state, per-gt mean area / validity ----
    {
        uint4 z = make_uint4(0u, 0u, 0u, 0u);
        for (int i = tid; i < PP / 4; i += TPB) ((uint4*)s_pack)[i] = z;
    }
    if (tid < NGT) {
        const float* bx = gt_boxes + (size_t)(b * NGT + tid) * TT * 4;
        float a[TT];
        int anyPos = 0;
        for (int f = 0; f < TT; f++) {
            float w = __fsub_rn(bx[f * 4 + 2], bx[f * 4 + 0]);
            float h = __fsub_rn(bx[f * 4 + 3], bx[f * 4 + 1]);
            a[f] = __fmul_rn(w, h);
            anyPos |= (w > 0.0f && h > 0.0f) ? 1 : 0;
        }
        // numpy pairwise sum order for n=8, then * 1/8
        float s = __fadd_rn(__fadd_rn(__fadd_rn(a[0], a[1]), __fadd_rn(a[2], a[3])),
                            __fadd_rn(__fadd_rn(a[4], a[5]), __fadd_rn(a[6], a[7])));
        s_area[tid]  = __fmul_rn(s, 0.125f);
        s_valid[tid] = (anyPos && gt_labels[b * NGT + tid] >= 0) ? 1 : 0;
        s_any[tid]   = 0;
    }
    __syncthreads();

    // ---- phase 1: stable ascending argsort by rank counting ----
    if (tid < NGT) {
        float an = s_area[tid];
        int r = 0;
        for (int m2 = 0; m2 < NGT; m2++) {
            float am = s_area[m2];
            r += (am < an || (am == an && m2 < tid)) ? 1 : 0;
        }
        s_order[r] = tid;
    }
    __syncthreads();

    // ---- phase 2: per sorted slot, this frame's geometry/meta ----
    if (tid < NGT) {
        int n   = s_order[tid];
        int src = b * NGT + n;
        s_geo[tid] = make_geo(gt_boxes, b, n, t);
        int id = gt_ids[src * TT + t];
        int4 mm;
        mm.x = gt_labels[src];
        mm.y = id;
        mm.z = (s_valid[n] && id != -1) ? 1 : 0;
        mm.w = n;                              // raw index for score recompute
        s_meta[tid] = mm;
    }
    // loop-top barrier covers phase-2 visibility for n=0

    for (int n = 0; n < NGT; n++) {
        __syncthreads();                       // A: prior claims + phase data visible
        int4 m = s_meta[n];
        if (!m.z) continue;                    // uniform across block
        float4 g = s_geo[n];

        // conservative rect: superset of {d < 0.5} (|dx_n| < sqrt(0.5) per axis), +slop
        float ex = __fmul_rn(g.z, 0.70711f);
        float ey = __fmul_rn(g.w, 0.70711f);
        int x0 = max(0,   (int)floorf((g.x - ex) * 160.0f - 0.5f) - 1);
        int x1 = min(159, (int)ceilf ((g.x + ex) * 160.0f - 0.5f) + 1);
        int y0 = max(0,   (int)floorf((g.y - ey) * 160.0f - 0.5f) - 1);
        int y1 = min(159, (int)ceilf ((g.y + ey) * 160.0f - 0.5f) + 1);
        int rw = x1 - x0 + 1;
        int M  = rw * (y1 - y0 + 1);           // <= ~72*72 < 6*TPB

        // pass 1: any unclaimed inner point? cache d in registers for pass 2.
        float dcache[6];
        int found = 0;
        {
            int k = 0;
            for (int i = tid; i < M; i += TPB, k++) {
                int r  = i / rw;
                int px = x0 + (i - r * rw);
                int py = y0 + r;
                int p  = py * 160 + px;
                float d = SUPP;
                if (!(s_pack[p] & PK_CLAIM)) {
                    d = point_dist(px, py, g);
                    if (d < INNER_TH) found = 1;
                }
                dcache[k] = d;
            }
        }
        if (found) s_any[n] = 1;
        __syncthreads();                       // B (no state writes between A..B scans)
        int any = s_any[n];

        if (any) {
            // pass 2: claim all unclaimed inner points (d cached; claimed-state
            // unchanged since pass 1; each p scanned by exactly one thread)
            unsigned base = PK_CLAIM | ((unsigned)m.x << PK_LAB_SH) |
                            ((unsigned)m.y << PK_ID_SH) | PK_MDV |
                            ((unsigned)m.x << PK_MDC_SH) |
                            ((unsigned)m.w << PK_MDN_SH);
            int k = 0;
            for (int i = tid; i < M; i += TPB, k++) {
                if (dcache[k] < INNER_TH) {    // implies was-unclaimed in pass 1
                    int r  = i / rw;
                    int px = x0 + (i - r * rw);
                    int p  = (y0 + r) * 160 + px;
                    s_pack[p] = base;          // score recomputed in paint from (n,p)
                }
            }
        } else {
            // fallback: single argmin over suppressed full frame (exact ref semantics:
            // claimed points hold 1e9; ties -> first index).
            unsigned long long key = ~0ULL;
            for (int p = tid; p < PP; p += TPB) {
                float deff;
                if (s_pack[p] & PK_CLAIM) {
                    deff = SUPP;
                } else {
                    int py = p / 160;
                    int px = p - py * 160;
                    deff = point_dist(px, py, g);
                }
                unsigned long long kk =
                    ((unsigned long long)__float_as_uint(deff) << 32) |
                    (unsigned long long)(unsigned)p;
                key = (kk < key) ? kk : key;
            }
            unsigned long long v = key;
            for (int off = 32; off > 0; off >>= 1) {
                unsigned long long o = shfl_down_u64(v, off);
                v = (o < v) ? o : v;
            }
            int lane = tid & 63, wave = tid >> 6;
            if (lane == 0) s_wave[wave] = v;
            __syncthreads();
            if (tid == 0) {
                unsigned long long mval = s_wave[0];
                for (int w = 1; w < 16; w++) mval = (s_wave[w] < mval) ? s_wave[w] : mval;
                s_bcast = mval;
            }
            __syncthreads();
            unsigned long long gmin = s_bcast;
            float minv = __uint_as_float((unsigned)(gmin >> 32));
            int minp = (int)(unsigned)(gmin & 0xffffffffu);
            if ((minp & (TPB - 1)) == tid) {   // unique owner thread
                unsigned npk = PK_CLAIM | ((unsigned)m.x << PK_LAB_SH) |
                               ((unsigned)m.y << PK_ID_SH);
                if (minv < SUPP) {
                    // winner was unclaimed: d >= 0.5 everywhere unclaimed => ref md
                    // write = 0 on an all-zero row: no md record.
                    s_pack[minp] = npk;
                } else {
                    // all points claimed (argmin of all-1e9 = index 0). ref writes
                    // md[minp][lab] = 0: erase prior record iff same class.
                    unsigned old = s_pack[minp];
                    unsigned mdbits = old & (PK_MDV | (63u << PK_MDC_SH) | (31u << PK_MDN_SH));
                    if ((old & PK_MDV) &&
                        ((old >> PK_MDC_SH) & 63u) == (unsigned)m.x) mdbits = 0u;
                    s_pack[minp] = npk | mdbits;
                }
            }
            // claims + s_wave reuse guarded by barrier A next iteration
        }
    }

    // ---- dump pack state (coalesced, only global traffic of this kernel) ----
    __syncthreads();
    uint4* dst = (uint4*)(packs_g + (size_t)bt * PP);
    for (int i = tid; i < PP / 4; i += TPB) dst[i] = ((const uint4*)s_pack)[i];
}

// ---------------- paint: write ml | md | mi, every output byte exactly once ----------
__global__ __launch_bounds__(256) void paint_kernel(
        const unsigned* __restrict__ packs,
        const float*    __restrict__ gt_boxes,
        float4* __restrict__ out4) {
    const int ML4  = BB * TT * PP / 4;            // 204800
    const int MD4  = BB * TT * PP * CC / 4;       // 8192000
    const int TOT4 = ML4 + MD4 + ML4;             // 8601600
    int stride = gridDim.x * blockDim.x;
    for (int j = blockIdx.x * blockDim.x + threadIdx.x; j < TOT4; j += stride) {
        float4 v;
        if (j < ML4) {                            // ml: label or -1
            int p4 = j << 2;
#pragma unroll
            for (int k = 0; k < 4; k++) {
                unsigned pk = packs[p4 + k];
                ((float*)&v)[k] = (pk & PK_CLAIM)
                    ? (float)((pk >> PK_LAB_SH) & 63u) : -1.0f;
            }
        } else if (j < ML4 + MD4) {               // md: one-hot score row
            unsigned idx = (unsigned)(j - ML4);
            unsigned pt  = idx / 10u;             // 10 float4s per point (40 classes)
            int c0 = (int)(idx - pt * 10u) << 2;
            unsigned pk = packs[pt];
            v = make_float4(0.0f, 0.0f, 0.0f, 0.0f);
            if (pk & PK_MDV) {
                int mc = (int)((pk >> PK_MDC_SH) & 63u);
                if (mc >= c0 && mc < c0 + 4) {
                    // exact score recompute: same IEEE ops as the match path
                    int n  = (int)((pk >> PK_MDN_SH) & 31u);
                    int bt = (int)(pt / PP);
                    int p  = (int)(pt - (unsigned)bt * PP);
                    float4 g = make_geo(gt_boxes, bt >> 3, n, bt & 7);
                    float d = point_dist(p - (p / 160) * 160, p / 160, g);
                    ((float*)&v)[mc - c0] = __fsub_rn(1.0f, __fmul_rn(2.0f, d));
                }
            }
        } else {                                  // mi: id or -1
            int p4 = (j - ML4 - MD4) << 2;
#pragma unroll
            for (int k = 0; k < 4; k++) {
                unsigned pk = packs[p4 + k];
                ((float*)&v)[k] = (pk & PK_CLAIM)
                    ? (float)((pk >> PK_ID_SH) & 127u) : -1.0f;
            }
        }
        out4[j] = v;
    }
}

extern "C" void kernel_launch(void* const* d_in, const int* in_sizes, int n_in,
                              void* d_out, int out_size, void* d_ws, size_t ws_size,
                              hipStream_t stream) {
    const int*   gt_labels = (const int*)d_in[0];
    const float* gt_boxes  = (const float*)d_in[1];
    const int*   gt_ids    = (const int*)d_in[2];
    // d_in[3] = ref_points (regular 160x160 grid — computed exactly in-kernel)
    // d_in[4] = spatial_shapes (unused; H=W=160 fixed)

    unsigned* packs = (unsigned*)d_ws;            // 3.2 MB

    match_kernel<<<BB * TT, TPB, 0, stream>>>(gt_labels, gt_boxes, gt_ids, packs);
    paint_kernel<<<8400, 256, 0, stream>>>(packs, gt_boxes, (float4*)d_out);
}

// Round 7
// 224.696 us; speedup vs baseline: 1.1332x; 1.0164x over previous
//
#include <hip/hip_runtime.h>

#define BB   4
#define NGT  20
#define TT   8
#define PP   25600
#define CC   40
#define TPB  1024
#define SUPP 1e9f
#define INNER_TH 0.5f

// pack bits: [0]=claimed [1:6]=ml label [7:13]=mi id [14]=md valid
//            [15:20]=md class [21:25]=md raw-gt-index (for exact score recompute)
#define PK_CLAIM  1u
#define PK_LAB_SH 1
#define PK_ID_SH  7
#define PK_MDV    (1u << 14)
#define PK_MDC_SH 15
#define PK_MDN_SH 21

__device__ inline unsigned long long shfl_down_u64(unsigned long long v, int off) {
    unsigned lo = (unsigned)v, hi = (unsigned)(v >> 32);
    lo = __shfl_down(lo, off, 64);
    hi = __shfl_down(hi, off, 64);
    return ((unsigned long long)hi << 32) | (unsigned long long)lo;
}

// geometry for (b, raw n, t) — identical IEEE ops in match and paint
__device__ inline float4 make_geo(const float* __restrict__ gt_boxes, int b, int n, int t) {
    const float* bx = gt_boxes + ((size_t)(b * NGT + n) * TT + t) * 4;
    float x1 = bx[0], y1 = bx[1], x2 = bx[2], y2 = bx[3];
    float4 g;
    g.x = __fmul_rn(__fadd_rn(x1, x2), 0.5f);
    g.y = __fmul_rn(__fadd_rn(y1, y2), 0.5f);
    g.z = fmaxf(__fsub_rn(x2, x1), 0.05f);
    g.w = fmaxf(__fsub_rn(y2, y1), 0.05f);
    return g;
}

// exact distance for grid point (px,py) vs gt geometry g — identical IEEE ops to ref
__device__ inline float point_dist(int px, int py, float4 g) {
    float rxv = __fdiv_rn((float)px + 0.5f, 160.0f);  // == ref_points formula exactly
    float ryv = __fdiv_rn((float)py + 0.5f, 160.0f);
    float dx = __fdiv_rn(__fsub_rn(g.x, rxv), g.z);
    float dy = __fdiv_rn(__fsub_rn(g.y, ryv), g.w);
    return __fadd_rn(__fmul_rn(dx, dx), __fmul_rn(dy, dy));  // no FMA contraction
}

// ---------------- match: one block per (b,t); pure-LDS loop; one coalesced dump ----
__global__ __launch_bounds__(TPB) void match_kernel(
        const int*   __restrict__ gt_labels,
        const float* __restrict__ gt_boxes,
        const int*   __restrict__ gt_ids,
        unsigned* __restrict__ packs_g) {  // [B*T][P]
    int bt = blockIdx.x;            // b*T + t
    int b  = bt >> 3;
    int t  = bt & 7;
    int tid = threadIdx.x;

    __shared__ unsigned s_pack[PP];           // 102400 B
    __shared__ float  s_area[NGT];
    __shared__ int    s_valid[NGT];
    __shared__ int    s_order[NGT];
    __shared__ int    s_any[NGT];             // one flag per gt: never reused
    __shared__ float4 s_geo[NGT];
    __shared__ int4   s_meta[NGT];            // {label, id, active, raw n}
    __shared__ unsigned long long s_wave[16];
    __shared__ unsigned long long s_bcast;

    // ---- phase 0: zero pack state, per-gt mean area / validity ----
    {
        uint4 z = make_uint4(0u, 0u, 0u, 0u);
        for (int i = tid; i < PP / 4; i += TPB) ((uint4*)s_pack)[i] = z;
    }
    if (tid < NGT) {
        const float* bx = gt_boxes + (size_t)(b * NGT + tid) * TT * 4;
        float a[TT];
        int anyPos = 0;
        for (int f = 0; f < TT; f++) {
            float w = __fsub_rn(bx[f * 4 + 2], bx[f * 4 + 0]);
            float h = __fsub_rn(bx[f * 4 + 3], bx[f * 4 + 1]);
            a[f] = __fmul_rn(w, h);
            anyPos |= (w > 0.0f && h > 0.0f) ? 1 : 0;
        }
        // numpy pairwise sum order for n=8, then * 1/8
        float s = __fadd_rn(__fadd_rn(__fadd_rn(a[0], a[1]), __fadd_rn(a[2], a[3])),
                            __fadd_rn(__fadd_rn(a[4], a[5]), __fadd_rn(a[6], a[7])));
        s_area[tid]  = __fmul_rn(s, 0.125f);
        s_valid[tid] = (anyPos && gt_labels[b * NGT + tid] >= 0) ? 1 : 0;
        s_any[tid]   = 0;
    }
    __syncthreads();

    // ---- phase 1: stable ascending argsort by rank counting ----
    if (tid < NGT) {
        float an = s_area[tid];
        int r = 0;
        for (int m2 = 0; m2 < NGT; m2++) {
            float am = s_area[m2];
            r += (am < an || (am == an && m2 < tid)) ? 1 : 0;
        }
        s_order[r] = tid;
    }
    __syncthreads();

    // ---- phase 2: per sorted slot, this frame's geometry/meta ----
    if (tid < NGT) {
        int n   = s_order[tid];
        int src = b * NGT + n;
        s_geo[tid] = make_geo(gt_boxes, b, n, t);
        int id = gt_ids[src * TT + t];
        int4 mm;
        mm.x = gt_labels[src];
        mm.y = id;
        mm.z = (s_valid[n] && id != -1) ? 1 : 0;
        mm.w = n;                              // raw index for score recompute
        s_meta[tid] = mm;
    }
    // loop-top barrier covers phase-2 visibility for n=0

    for (int n = 0; n < NGT; n++) {
        __syncthreads();                       // A: prior claims + phase data visible
        int4 m = s_meta[n];
        if (!m.z) continue;                    // uniform across block
        float4 g = s_geo[n];

        // conservative rect: superset of {d < 0.5} (|dx_n| < sqrt(0.5) per axis), +slop
        float ex = __fmul_rn(g.z, 0.70711f);
        float ey = __fmul_rn(g.w, 0.70711f);
        int x0 = max(0,   (int)floorf((g.x - ex) * 160.0f - 0.5f) - 1);
        int x1 = min(159, (int)ceilf ((g.x + ex) * 160.0f - 0.5f) + 1);
        int y0 = max(0,   (int)floorf((g.y - ey) * 160.0f - 0.5f) - 1);
        int y1 = min(159, (int)ceilf ((g.y + ey) * 160.0f - 0.5f) + 1);
        int rw = x1 - x0 + 1;
        int M  = rw * (y1 - y0 + 1);           // <= ~72*72 < 6*TPB

        // pass 1: any unclaimed inner point? cache d in registers for pass 2.
        float dcache[6];
        int found = 0;
        {
            int k = 0;
            for (int i = tid; i < M; i += TPB, k++) {
                int r  = i / rw;
                int px = x0 + (i - r * rw);
                int py = y0 + r;
                int p  = py * 160 + px;
                float d = SUPP;
                if (!(s_pack[p] & PK_CLAIM)) {
                    d = point_dist(px, py, g);
                    if (d < INNER_TH) found = 1;
                }
                dcache[k] = d;
            }
        }
        if (found) s_any[n] = 1;
        __syncthreads();                       // B (no state writes between A..B scans)
        int any = s_any[n];

        if (any) {
            // pass 2: claim all unclaimed inner points (d cached; claimed-state
            // unchanged since pass 1; each p scanned by exactly one thread)
            unsigned base = PK_CLAIM | ((unsigned)m.x << PK_LAB_SH) |
                            ((unsigned)m.y << PK_ID_SH) | PK_MDV |
                            ((unsigned)m.x << PK_MDC_SH) |
                            ((unsigned)m.w << PK_MDN_SH);
            int k = 0;
            for (int i = tid; i < M; i += TPB, k++) {
                if (dcache[k] < INNER_TH) {    // implies was-unclaimed in pass 1
                    int r  = i / rw;
                    int px = x0 + (i - r * rw);
                    int p  = (y0 + r) * 160 + px;
                    s_pack[p] = base;          // score recomputed in paint from (n,p)
                }
            }
        } else {
            // fallback: single argmin over suppressed full frame (exact ref semantics:
            // claimed points hold 1e9; ties -> first index).
            unsigned long long key = ~0ULL;
            for (int p = tid; p < PP; p += TPB) {
                float deff;
                if (s_pack[p] & PK_CLAIM) {
                    deff = SUPP;
                } else {
                    int py = p / 160;
                    int px = p - py * 160;
                    deff = point_dist(px, py, g);
                }
                unsigned long long kk =
                    ((unsigned long long)__float_as_uint(deff) << 32) |
                    (unsigned long long)(unsigned)p;
                key = (kk < key) ? kk : key;
            }
            unsigned long long v = key;
            for (int off = 32; off > 0; off >>= 1) {
                unsigned long long o = shfl_down_u64(v, off);
                v = (o < v) ? o : v;
            }
            int lane = tid & 63, wave = tid >> 6;
            if (lane == 0) s_wave[wave] = v;
            __syncthreads();
            if (tid == 0) {
                unsigned long long mval = s_wave[0];
                for (int w = 1; w < 16; w++) mval = (s_wave[w] < mval) ? s_wave[w] : mval;
                s_bcast = mval;
            }
            __syncthreads();
            unsigned long long gmin = s_bcast;
            float minv = __uint_as_float((unsigned)(gmin >> 32));
            int minp = (int)(unsigned)(gmin & 0xffffffffu);
            if ((minp & (TPB - 1)) == tid) {   // unique owner thread
                unsigned npk = PK_CLAIM | ((unsigned)m.x << PK_LAB_SH) |
                               ((unsigned)m.y << PK_ID_SH);
                if (minv < SUPP) {
                    // winner was unclaimed: d >= 0.5 everywhere unclaimed => ref md
                    // write = 0 on an all-zero row: no md record.
                    s_pack[minp] = npk;
                } else {
                    // all points claimed (argmin of all-1e9 = index 0). ref writes
                    // md[minp][lab] = 0: erase prior record iff same class.
                    unsigned old = s_pack[minp];
                    unsigned mdbits = old & (PK_MDV | (63u << PK_MDC_SH) | (31u << PK_MDN_SH));
                    if ((old & PK_MDV) &&
                        ((old >> PK_MDC_SH) & 63u) == (unsigned)m.x) mdbits = 0u;
                    s_pack[minp] = npk | mdbits;
                }
            }
            // claims + s_wave reuse guarded by barrier A next iteration
        }
    }

    // ---- dump pack state (coalesced, only global traffic of this kernel) ----
    __syncthreads();
    uint4* dst = (uint4*)(packs_g + (size_t)bt * PP);
    for (int i = tid; i < PP / 4; i += TPB) dst[i] = ((const uint4*)s_pack)[i];
}

// ---------------- paint: md via LDS-staged 256-point tiles; ml/mi via uint4 packs ----
// blocks [0, MD_BLOCKS): md tiles. blocks [MD_BLOCKS, MD_BLOCKS+MLMI_BLOCKS): ml+mi.
#define MD_BLOCKS   3200   // 819200 points / 256 per tile
#define MLMI_BLOCKS 400    // 409600 float4s / (256 threads * 4 rounds)
__global__ __launch_bounds__(256) void paint_kernel(
        const unsigned* __restrict__ packs,
        const float*    __restrict__ gt_boxes,
        float4* __restrict__ out4) {
    const int ML4 = BB * TT * PP / 4;             // 204800 float4s
    const int MD4 = BB * TT * PP * CC / 4;        // 8192000 float4s
    int bi  = blockIdx.x;
    int tid = threadIdx.x;

    if (bi < MD_BLOCKS) {
        // ---- md tile: 256 points -> 2560 contiguous float4s ----
        __shared__ int   s_cls[256];
        __shared__ float s_sc[256];
        int pt = bi * 256 + tid;                  // global point index
        unsigned pk = packs[pt];
        int   cls = -1;
        float sc  = 0.0f;
        if (pk & PK_MDV) {
            cls = (int)((pk >> PK_MDC_SH) & 63u);
            int n  = (int)((pk >> PK_MDN_SH) & 31u);
            int bt = pt / PP;
            int p  = pt - bt * PP;
            float4 g = make_geo(gt_boxes, bt >> 3, n, bt & 7);
            float d  = point_dist(p - (p / 160) * 160, p / 160, g);
            sc = __fsub_rn(1.0f, __fmul_rn(2.0f, d));   // exact: same ops as ref
        }
        s_cls[tid] = cls;
        s_sc[tid]  = sc;
        __syncthreads();
        float4* dst = out4 + ML4 + (size_t)bi * 2560;
#pragma unroll
        for (int r = 0; r < 10; r++) {
            int f   = r * 256 + tid;              // float4 within tile
            int ptl = f / 10;                     // local point
            int c0  = (f - ptl * 10) << 2;        // first class of this float4
            int c   = s_cls[ptl];
            float4 v = make_float4(0.0f, 0.0f, 0.0f, 0.0f);
            if (c >= c0 && c < c0 + 4) ((float*)&v)[c - c0] = s_sc[ptl];
            dst[f] = v;
        }
    } else {
        // ---- ml + mi: each thread 4 float4s, 16B pack load per float4 ----
        int base = (bi - MD_BLOCKS) * 1024;       // float4 index in [0, 409600)
#pragma unroll
        for (int r = 0; r < 4; r++) {
            int f = base + r * 256 + tid;
            int isMi = (f >= ML4);
            int pf = isMi ? (f - ML4) : f;        // pack float4 index
            uint4 pk4 = ((const uint4*)packs)[pf];
            float4 v;
            int sh = isMi ? PK_ID_SH : PK_LAB_SH;
            unsigned msk = isMi ? 127u : 63u;
            v.x = (pk4.x & PK_CLAIM) ? (float)((pk4.x >> sh) & msk) : -1.0f;
            v.y = (pk4.y & PK_CLAIM) ? (float)((pk4.y >> sh) & msk) : -1.0f;
            v.z = (pk4.z & PK_CLAIM) ? (float)((pk4.z >> sh) & msk) : -1.0f;
            v.w = (pk4.w & PK_CLAIM) ? (float)((pk4.w >> sh) & msk) : -1.0f;
            out4[isMi ? (ML4 + MD4 + pf) : f] = v;
        }
    }
}

extern "C" void kernel_launch(void* const* d_in, const int* in_sizes, int n_in,
                              void* d_out, int out_size, void* d_ws, size_t ws_size,
                              hipStream_t stream) {
    const int*   gt_labels = (const int*)d_in[0];
    const float* gt_boxes  = (const float*)d_in[1];
    const int*   gt_ids    = (const int*)d_in[2];
    // d_in[3] = ref_points (regular 160x160 grid — computed exactly in-kernel)
    // d_in[4] = spatial_shapes (unused; H=W=160 fixed)

    unsigned* packs = (unsigned*)d_ws;            // 3.2 MB

    match_kernel<<<BB * TT, TPB, 0, stream>>>(gt_labels, gt_boxes, gt_ids, packs);
    paint_kernel<<<MD_BLOCKS + MLMI_BLOCKS, 256, 0, stream>>>(packs, gt_boxes,
                                                              (float4*)d_out);
}